// Round 2
// baseline (906.291 us; speedup 1.0000x reference)
//
#include <hip/hip_runtime.h>
#include <cmath>

#define T_TOKENS 16384   // B*S
#define DIM 2048
#define HH 64            // complexity hidden
#define NG 4             // groups
#define EPG 16
#define NE 64            // experts
#define NJ 132           // 64 h + 4 group + 64 expert logits
#define DSPLIT 8
#define DCHUNK (DIM / DSPLIT)   // 256 d per block
#define OT_STRIDE 133

// ws layout (floats), STORE path:
//   [0 .. DSPLIT*NJ*T_TOKENS)  partial logits, indexed [part][j][token]
//   then 128 floats: expert sums (usage, router-prob)
// ATOMIC fallback path: [NJ*T_TOKENS) logits [j][token], then 128 sums.

__global__ void moe_zero(float* p, size_t n) {
    size_t i = (size_t)blockIdx.x * blockDim.x + threadIdx.x;
    size_t stride = (size_t)gridDim.x * blockDim.x;
    for (; i < n; i += stride) p[i] = 0.f;
}

// 8 FMAs: one weight row chunk (8 floats, wave-uniform -> s_load) times x (float4 pair)
#define ROW8(accv, wrow) do { const float* _w = (wrow);              \
    accv = fmaf(_w[0], a.x, accv); accv = fmaf(_w[1], a.y, accv);    \
    accv = fmaf(_w[2], a.z, accv); accv = fmaf(_w[3], a.w, accv);    \
    accv = fmaf(_w[4], b.x, accv); accv = fmaf(_w[5], b.y, accv);    \
    accv = fmaf(_w[6], b.z, accv); accv = fmaf(_w[7], b.w, accv); } while (0)

template <bool ATOMIC>
__global__ __launch_bounds__(256, 2) void moe_logits(
    const float* __restrict__ x, const float* __restrict__ Wg,
    const float* __restrict__ We, const float* __restrict__ W1,
    float* __restrict__ wsl)
{
    const int bid  = blockIdx.x;
    const int tgrp = bid & 63;        // 64 token groups of 256
    const int dgrp = bid >> 6;        // DSPLIT d groups
    const int tok  = tgrp * 256 + threadIdx.x;   // one token per thread
    const int D0   = dgrp * DCHUNK;

    const float4* xp  = (const float4*)(x + (size_t)tok * DIM + D0);
    const float*  w1p = W1 + D0;      // [64][DIM]
    const float*  wgp = Wg + D0;      // [4][DIM]
    const float*  wep = We + D0;      // [4][16][DIM] == [64][DIM] flat

    float acc[NJ];
    #pragma unroll
    for (int j = 0; j < NJ; ++j) acc[j] = 0.f;

    float4 xa = xp[0], xb = xp[1];
    #pragma unroll 1
    for (int s = 0; s < DCHUNK / 8; ++s) {
        const float4 a = xa, b = xb;
        const int sn = (s < DCHUNK / 8 - 1) ? s + 1 : s;   // safe prefetch
        xa = xp[sn * 2]; xb = xp[sn * 2 + 1];
        const int dd = s * 8;
        const float* w1d = w1p + dd;
        #pragma unroll
        for (int j = 0; j < HH; ++j) ROW8(acc[j], w1d + (size_t)j * DIM);
        const float* wgd = wgp + dd;
        #pragma unroll
        for (int g = 0; g < NG; ++g) ROW8(acc[HH + g], wgd + (size_t)g * DIM);
        const float* wed = wep + dd;
        #pragma unroll
        for (int e = 0; e < NE; ++e) ROW8(acc[HH + NG + e], wed + (size_t)e * DIM);
    }

    if (ATOMIC) {
        #pragma unroll
        for (int j = 0; j < NJ; ++j)
            atomicAdd(&wsl[(size_t)j * T_TOKENS + tok], acc[j]);
    } else {
        float* dst = wsl + (size_t)dgrp * NJ * T_TOKENS + tok;
        #pragma unroll
        for (int j = 0; j < NJ; ++j)
            dst[(size_t)j * T_TOKENS] = acc[j];   // lane-coalesced dword stores
    }
}

// epilogue: 256 blocks x 64 tokens. P = number of partials to sum (1 or DSPLIT).
__global__ __launch_bounds__(256, 2) void moe_epilogue(
    const float* __restrict__ wsl, int P,
    const float* __restrict__ b1, const float* __restrict__ W2,
    const float* __restrict__ b2, const int* __restrict__ minE,
    const int* __restrict__ maxE, float* __restrict__ out,
    float* __restrict__ ws_sums)
{
    __shared__ float ot[64 * OT_STRIDE];
    __shared__ float rp_s[64 * 17];
    __shared__ float sc_n1[64], sc_n2[64], sc_u2[64];
    __shared__ int   sc_e1[64], sc_e2[64], sc_g[64];
    __shared__ float s_usage[NE], s_rp[NE];

    const int tid = threadIdx.x;
    const int T0  = blockIdx.x * 64;
    if (tid < NE) { s_usage[tid] = 0.f; s_rp[tid] = 0.f; }

    // gather logits: ws [p][j][token] -> lds [t][j]
    for (int idx = tid; idx < 64 * NJ; idx += 256) {
        int j = idx >> 6, t = idx & 63;       // consecutive tid -> consecutive t (coalesced)
        float v = 0.f;
        for (int p = 0; p < P; ++p)
            v += wsl[((size_t)p * NJ + j) * T_TOKENS + T0 + t];
        ot[t * OT_STRIDE + j] = v;
    }
    __syncthreads();

    if (tid < 64) {
        const int t = tid;
        const float* o = &ot[t * OT_STRIDE];

        float z = b2[0];
        #pragma unroll 8
        for (int i = 0; i < HH; ++i) {
            float h = o[i] + b1[i];
            h = h > 0.f ? h : 0.f;
            z = fmaf(W2[i], h, z);
        }
        float c = 1.f / (1.f + expf(-z));
        int mx = maxE[0], mn = minE[0];
        int k = (int)(c * (float)mx);
        k = k < mn ? mn : k; k = k > mx ? mx : k;
        float u2 = (k >= 2) ? 1.f : 0.f;

        float gm = -INFINITY; int gidx = 0;
        float gl[NG];
        #pragma unroll
        for (int g = 0; g < NG; ++g) {
            gl[g] = o[HH + g];
            if (gl[g] > gm) { gm = gl[g]; gidx = g; }
        }
        float gsum = 0.f;
        #pragma unroll
        for (int g = 0; g < NG; ++g) gsum += expf(gl[g] - gm);
        float gp_max = 1.f / gsum;

        float el[EPG]; float em = -INFINITY;
        #pragma unroll
        for (int j = 0; j < EPG; ++j) {
            el[j] = o[HH + NG + gidx * EPG + j];
            em = fmaxf(em, el[j]);
        }
        float ep[EPG]; float es = 0.f;
        #pragma unroll
        for (int j = 0; j < EPG; ++j) { ep[j] = expf(el[j] - em); es += ep[j]; }
        float inv_es = 1.f / es;
        #pragma unroll
        for (int j = 0; j < EPG; ++j) ep[j] *= inv_es;

        float v1 = -1.f; int i1 = 0;
        #pragma unroll
        for (int j = 0; j < EPG; ++j) if (ep[j] > v1) { v1 = ep[j]; i1 = j; }
        float v2 = -1.f; int i2 = 0;
        #pragma unroll
        for (int j = 0; j < EPG; ++j) if (j != i1 && ep[j] > v2) { v2 = ep[j]; i2 = j; }

        float denom = v1 + v2 * u2;
        sc_n1[t] = v1 / denom; sc_n2[t] = v2 * u2 / denom; sc_u2[t] = u2;
        sc_e1[t] = gidx * EPG + i1; sc_e2[t] = gidx * EPG + i2; sc_g[t] = gidx;
        #pragma unroll
        for (int j = 0; j < EPG; ++j) rp_s[t * 17 + j] = gp_max * ep[j];
    }
    __syncthreads();

    float* outD = out;
    float* outC = out + (size_t)T_TOKENS * NE;
    float* outR = out + (size_t)2 * T_TOKENS * NE;
    for (int idx = tid; idx < 64 * NE; idx += 256) {
        int t = idx >> 6, e = idx & 63;
        int e1 = sc_e1[t], e2 = sc_e2[t];
        float disp = (e == e1 ? 1.f : 0.f) + (e == e2 ? sc_u2[t] : 0.f);
        float comb = (e == e1 ? sc_n1[t] : 0.f) + (e == e2 ? sc_n2[t] : 0.f);
        float rpv  = ((e >> 4) == sc_g[t]) ? rp_s[t * 17 + (e & 15)] : 0.f;
        size_t o = (size_t)(T0 + t) * NE + e;
        outD[o] = disp; outC[o] = comb; outR[o] = rpv;
        atomicAdd(&s_usage[e], disp);
        atomicAdd(&s_rp[e], rpv);
    }
    __syncthreads();
    if (tid < NE) {
        atomicAdd(&ws_sums[tid], s_usage[tid]);
        atomicAdd(&ws_sums[NE + tid], s_rp[tid]);
    }
}

__global__ void moe_finalize(const float* __restrict__ ws_sums, float* __restrict__ out) {
    int l = threadIdx.x;  // 64 threads
    float v = ws_sums[l] * ws_sums[NE + l];
    #pragma unroll
    for (int off = 32; off; off >>= 1) v += __shfl_down(v, off, 64);
    if (l == 0) {
        float N = (float)T_TOKENS;
        out[(size_t)3 * T_TOKENS * NE] = v * (float)NE / (N * N);
    }
}

extern "C" void kernel_launch(void* const* d_in, const int* in_sizes, int n_in,
                              void* d_out, int out_size, void* d_ws, size_t ws_size,
                              hipStream_t stream) {
    const float* x  = (const float*)d_in[0];
    const float* Wg = (const float*)d_in[1];
    const float* We = (const float*)d_in[2];
    const float* W1 = (const float*)d_in[3];
    const float* b1 = (const float*)d_in[4];
    const float* W2 = (const float*)d_in[5];
    const float* b2 = (const float*)d_in[6];
    const int* minE = (const int*)d_in[7];
    const int* maxE = (const int*)d_in[8];
    float* out = (float*)d_out;
    float* ws  = (float*)d_ws;

    const size_t storeFloats  = (size_t)DSPLIT * NJ * T_TOKENS;   // 17.3M floats
    const size_t atomicFloats = (size_t)NJ * T_TOKENS;            // 2.16M floats

    if (ws_size >= (storeFloats + 128) * sizeof(float)) {
        float* sums = ws + storeFloats;
        moe_zero<<<1, 128, 0, stream>>>(sums, 128);
        moe_logits<false><<<64 * DSPLIT, 256, 0, stream>>>(x, Wg, We, W1, ws);
        moe_epilogue<<<T_TOKENS / 64, 256, 0, stream>>>(ws, DSPLIT, b1, W2, b2,
                                                        minE, maxE, out, sums);
        moe_finalize<<<1, 64, 0, stream>>>(sums, out);
    } else {
        float* sums = ws + atomicFloats;
        moe_zero<<<512, 256, 0, stream>>>(ws, atomicFloats + 128);
        moe_logits<true><<<64 * DSPLIT, 256, 0, stream>>>(x, Wg, We, W1, ws);
        moe_epilogue<<<T_TOKENS / 64, 256, 0, stream>>>(ws, 1, b1, W2, b2,
                                                        minE, maxE, out, sums);
        moe_finalize<<<1, 64, 0, stream>>>(sums, out);
    }
}

// Round 3
// 263.483 us; speedup vs baseline: 3.4397x; 3.4397x over previous
//
#include <hip/hip_runtime.h>
#include <cmath>

#define T_TOKENS 16384
#define DIM 2048
#define HH 64
#define NG 4
#define EPG 16
#define NE 64
#define NJ 132
#define NJP 144          // padded to 9 n-tiles
#define NT 9
#define KS 2
#define KHALF (DIM / KS)       // 1024
#define KSTEPS (KHALF / 32)    // 32
#define TAU 0.02f
#define KEPS 5e-3f

typedef __attribute__((ext_vector_type(8))) short bf16x8;
typedef __attribute__((ext_vector_type(4))) float f32x4;

// ws float-offsets
#define WF_FLOATS (64 * NT * 64 * 4)                 // 147456 (fragment-linear bf16 weights)
#define P_OFF WF_FLOATS
#define P_FLOATS ((size_t)KS * T_TOKENS * NJP)       // 4718592
#define SUM_OFF (P_OFF + P_FLOATS)                   // 128 floats: usage, rp
#define CNT_OFF (SUM_OFF + 128)
#define LIST_OFF (CNT_OFF + 4)                       // int4 entries (16B aligned)

static __device__ inline unsigned bf16rne(float x) {
    unsigned u = __float_as_uint(x);
    return (u + 0x7FFFu + ((u >> 16) & 1u)) >> 16;
}
static __device__ inline unsigned pk2trunc(float a, float b) {
    return (__float_as_uint(a) >> 16) | (__float_as_uint(b) & 0xFFFF0000u);
}
static __device__ inline bf16x8 packA(float4 a, float4 b) {
    union { unsigned u[4]; bf16x8 v; } r;
    r.u[0] = pk2trunc(a.x, a.y); r.u[1] = pk2trunc(a.z, a.w);
    r.u[2] = pk2trunc(b.x, b.y); r.u[3] = pk2trunc(b.z, b.w);
    return r.v;
}

__global__ void moe_zero(float* sums, int* cnt) {
    if (threadIdx.x < 128) sums[threadIdx.x] = 0.f;
    if (threadIdx.x == 128) *cnt = 0;
}

// Build fragment-linear bf16 weight buffer: [kstep 64][ntile 9][lane 64][16B]
__global__ void moe_prep(const float* __restrict__ Wg, const float* __restrict__ We,
                         const float* __restrict__ W1, float* __restrict__ ws) {
    int bid = blockIdx.x;                 // 576
    int kstep = bid / NT, nt = bid % NT;
    int lane = threadIdx.x;               // 64
    int row = nt * 16 + (lane & 15);
    int k0 = kstep * 32 + (lane >> 4) * 8;
    const float* src = nullptr;
    if (row < HH)            src = W1 + (size_t)row * DIM;
    else if (row < HH + NG)  src = Wg + (size_t)(row - HH) * DIM;
    else if (row < NJ)       src = We + (size_t)(row - HH - NG) * DIM;
    unsigned r0 = 0, r1 = 0, r2 = 0, r3 = 0;
    if (src) {
        r0 = bf16rne(src[k0 + 0]) | (bf16rne(src[k0 + 1]) << 16);
        r1 = bf16rne(src[k0 + 2]) | (bf16rne(src[k0 + 3]) << 16);
        r2 = bf16rne(src[k0 + 4]) | (bf16rne(src[k0 + 5]) << 16);
        r3 = bf16rne(src[k0 + 6]) | (bf16rne(src[k0 + 7]) << 16);
    }
    ((uint4*)ws)[(size_t)(kstep * NT + nt) * 64 + lane] = make_uint4(r0, r1, r2, r3);
}

__global__ __launch_bounds__(256, 2) void moe_gemm(
    const float* __restrict__ x, const float* __restrict__ wfrag,
    float* __restrict__ part) {
    const int bid = blockIdx.x;
    const int ks = bid >> 8;             // grid = 256*KS
    const int mb = bid & 255;
    const int tid = threadIdx.x;
    const int lane = tid & 63, wave = tid >> 6;
    const int l15 = lane & 15, lq = lane >> 4;
    const int tokA = mb * 64 + wave * 16 + l15;
    const float4* xp = (const float4*)(x + (size_t)tokA * DIM + ks * KHALF + lq * 8);
    const bf16x8* wf = (const bf16x8*)wfrag + (size_t)(ks * KSTEPS) * NT * 64 + lane;

    f32x4 acc[NT];
    #pragma unroll
    for (int n = 0; n < NT; ++n) acc[n] = (f32x4){0.f, 0.f, 0.f, 0.f};

    float4 aA0 = xp[0], aA1 = xp[1];
    bf16x8 bA[NT], bB[NT];
    #pragma unroll
    for (int n = 0; n < NT; ++n) bA[n] = wf[n * 64];
    float4 aB0, aB1;

    #pragma unroll 2
    for (int t = 0; t < KSTEPS; t += 2) {
        const int t1 = (t + 1 < KSTEPS) ? t + 1 : t;
        aB0 = xp[t1 * 8]; aB1 = xp[t1 * 8 + 1];
        #pragma unroll
        for (int n = 0; n < NT; ++n) bB[n] = wf[(t1 * NT + n) * 64];
        bf16x8 af = packA(aA0, aA1);
        #pragma unroll
        for (int n = 0; n < NT; ++n)
            acc[n] = __builtin_amdgcn_mfma_f32_16x16x32_bf16(af, bA[n], acc[n], 0, 0, 0);

        const int t2 = (t + 2 < KSTEPS) ? t + 2 : t;
        aA0 = xp[t2 * 8]; aA1 = xp[t2 * 8 + 1];
        #pragma unroll
        for (int n = 0; n < NT; ++n) bA[n] = wf[(t2 * NT + n) * 64];
        af = packA(aB0, aB1);
        #pragma unroll
        for (int n = 0; n < NT; ++n)
            acc[n] = __builtin_amdgcn_mfma_f32_16x16x32_bf16(af, bB[n], acc[n], 0, 0, 0);
    }

    // C/D: col = lane&15 (n), row = (lane>>4)*4 + r (token)
    float* po = part + (size_t)ks * T_TOKENS * NJP
              + (size_t)(mb * 64 + wave * 16 + lq * 4) * NJP + l15;
    #pragma unroll
    for (int n = 0; n < NT; ++n)
        #pragma unroll
        for (int r = 0; r < 4; ++r)
            po[(size_t)r * NJP + n * 16] = acc[n][r];
}

__global__ __launch_bounds__(256, 2) void moe_epi(
    const float* __restrict__ part,
    const float* __restrict__ b1, const float* __restrict__ W2,
    const float* __restrict__ b2, const int* __restrict__ minE,
    const int* __restrict__ maxE, float* __restrict__ out,
    float* __restrict__ sums, int* __restrict__ cnt, int4* __restrict__ list) {
    __shared__ float ot[32 * 133];
    __shared__ float rp_s[32 * 17];
    __shared__ float sc_n1[32], sc_n2[32], sc_u2[32];
    __shared__ int   sc_e1[32], sc_e2[32], sc_g[32];
    __shared__ float s_usage[NE], s_rp[NE];
    const int tid = threadIdx.x;
    const int T0 = blockIdx.x * 32;
    if (tid < NE) { s_usage[tid] = 0.f; s_rp[tid] = 0.f; }

    for (int idx = tid; idx < 32 * NJ; idx += 256) {
        int t = idx / NJ, j = idx % NJ;
        float v = part[(size_t)(T0 + t) * NJP + j];
        #pragma unroll
        for (int p = 1; p < KS; ++p)
            v += part[(size_t)p * T_TOKENS * NJP + (size_t)(T0 + t) * NJP + j];
        ot[t * 133 + j] = v;
    }
    __syncthreads();

    if (tid < 32) {
        const int t = tid, tok = T0 + t;
        const float* o = &ot[t * 133];

        float z = b2[0];
        #pragma unroll 8
        for (int i = 0; i < HH; ++i) {
            float h = o[i] + b1[i];
            z = fmaf(W2[i], h > 0.f ? h : 0.f, z);
        }
        float c = 1.f / (1.f + expf(-z));
        int mx = maxE[0], mn = minE[0];
        float y = c * (float)mx;
        int k = (int)y; k = k < mn ? mn : (k > mx ? mx : k);
        int kl = (int)(y - KEPS); kl = kl < mn ? mn : (kl > mx ? mx : kl);
        int kh = (int)(y + KEPS); kh = kh < mn ? mn : (kh > mx ? mx : kh);
        bool flagK = (kl != kh);
        float u2 = (k >= 2) ? 1.f : 0.f;

        float gl[NG]; float gm = -INFINITY; int gi = 0;
        #pragma unroll
        for (int g = 0; g < NG; ++g) {
            gl[g] = o[HH + g];
            if (gl[g] > gm) { gm = gl[g]; gi = g; }
        }
        float g2 = -INFINITY;
        #pragma unroll
        for (int g = 0; g < NG; ++g) if (g != gi && gl[g] > g2) g2 = gl[g];
        bool flagG = (gm - g2) < TAU;
        float gsum = 0.f;
        #pragma unroll
        for (int g = 0; g < NG; ++g) gsum += expf(gl[g] - gm);
        float gp = 1.f / gsum;

        float el[EPG];
        #pragma unroll
        for (int j = 0; j < EPG; ++j) el[j] = o[HH + NG + gi * EPG + j];
        float e1 = -INFINITY, e2v = -INFINITY, e3v = -INFINITY; int i1 = 0, i2 = 0;
        #pragma unroll
        for (int j = 0; j < EPG; ++j) {
            float v = el[j];
            if (v > e1)       { e3v = e2v; e2v = e1; i2 = i1; e1 = v; i1 = j; }
            else if (v > e2v) { e3v = e2v; e2v = v; i2 = j; }
            else if (v > e3v) { e3v = v; }
        }
        bool flagE = ((e1 - e2v) < TAU) || (u2 > 0.f && (e2v - e3v) < TAU);

        float ep[EPG]; float es = 0.f;
        #pragma unroll
        for (int j = 0; j < EPG; ++j) { ep[j] = expf(el[j] - e1); es += ep[j]; }
        float inv = 1.f / es;
        #pragma unroll
        for (int j = 0; j < EPG; ++j) ep[j] *= inv;
        float v1 = ep[i1], v2 = ep[i2];
        float denom = v1 + v2 * u2;
        sc_n1[t] = v1 / denom; sc_n2[t] = v2 * u2 / denom; sc_u2[t] = u2;
        sc_e1[t] = gi * EPG + i1; sc_e2[t] = gi * EPG + i2; sc_g[t] = gi;
        #pragma unroll
        for (int j = 0; j < EPG; ++j) rp_s[t * 17 + j] = gp * ep[j];

        if (flagK || flagG || flagE) {
            int p = atomicAdd(cnt, 1);
            int fl = (flagG ? 1 : 0) | (flagE ? 2 : 0) | (flagK ? 4 : 0);
            list[p] = make_int4(tok, fl, (((int)u2) << 8) | gi, __float_as_int(gp));
        }
    }
    __syncthreads();

    float* outD = out;
    float* outC = out + (size_t)T_TOKENS * NE;
    float* outR = out + (size_t)2 * T_TOKENS * NE;
    for (int idx = tid; idx < 32 * NE; idx += 256) {
        int t = idx >> 6, e = idx & 63;
        int e1i = sc_e1[t], e2i = sc_e2[t];
        float disp = (e == e1i ? 1.f : 0.f) + (e == e2i ? sc_u2[t] : 0.f);
        float comb = (e == e1i ? sc_n1[t] : 0.f) + (e == e2i ? sc_n2[t] : 0.f);
        float rpv  = ((e >> 4) == sc_g[t]) ? rp_s[t * 17 + (e & 15)] : 0.f;
        size_t ob = (size_t)(T0 + t) * NE + e;
        outD[ob] = disp; outC[ob] = comb; outR[ob] = rpv;
        atomicAdd(&s_usage[e], disp);
        atomicAdd(&s_rp[e], rpv);
    }
    __syncthreads();
    if (tid < NE) {
        atomicAdd(&sums[tid], s_usage[tid]);
        atomicAdd(&sums[NE + tid], s_rp[tid]);
    }
}

__global__ __launch_bounds__(64, 1) void moe_fix(
    const float* __restrict__ x, const float* __restrict__ Wg,
    const float* __restrict__ We, const float* __restrict__ W1,
    const float* __restrict__ b1, const float* __restrict__ W2,
    const float* __restrict__ b2, const int* __restrict__ minE,
    const int* __restrict__ maxE, float* __restrict__ out,
    float* __restrict__ sums, const int* __restrict__ cnt,
    const int4* __restrict__ list) {
    const int lane = threadIdx.x;
    const int n = *cnt;
    for (int i = blockIdx.x; i < n; i += gridDim.x) {
        int4 ent = list[i];
        int tok = ent.x, fl = ent.y;
        int u2i = (ent.z >> 8) & 1, gi = ent.z & 255;
        float gp = __int_as_float(ent.w);

        float xr[32];
        const float* xrow = x + (size_t)tok * DIM;
        #pragma unroll
        for (int m = 0; m < 32; ++m) xr[m] = xrow[lane + m * 64];

        auto dotf = [&](const float* w) -> float {
            float s = 0.f;
            #pragma unroll
            for (int m = 0; m < 32; ++m) s = fmaf(xr[m], w[lane + m * 64], s);
            #pragma unroll
            for (int off = 32; off; off >>= 1) s += __shfl_xor(s, off, 64);
            return s;
        };

        if (fl & 4) {   // k uncertain: exact h, z, k
            float z = b2[0];
            for (int j = 0; j < HH; ++j) {
                float d = dotf(W1 + (size_t)j * DIM) + b1[j];
                z = fmaf(W2[j], d > 0.f ? d : 0.f, z);
            }
            float c = 1.f / (1.f + expf(-z));
            int mx = maxE[0], mn = minE[0];
            int k = (int)(c * (float)mx);
            k = k < mn ? mn : (k > mx ? mx : k);
            u2i = (k >= 2) ? 1 : 0;
        }
        if (fl & 1) {   // group uncertain: exact group logits
            float gl[NG]; float gm = -INFINITY; int gnew = 0;
            #pragma unroll
            for (int g = 0; g < NG; ++g) {
                gl[g] = dotf(Wg + (size_t)g * DIM);
                if (gl[g] > gm) { gm = gl[g]; gnew = g; }
            }
            gi = gnew;
            float gsum = 0.f;
            #pragma unroll
            for (int g = 0; g < NG; ++g) gsum += expf(gl[g] - gm);
            gp = 1.f / gsum;
        }
        // exact expert logits for chosen group
        float el[EPG]; float em = -INFINITY;
        for (int j = 0; j < EPG; ++j) {
            el[j] = dotf(We + (size_t)(gi * EPG + j) * DIM);
            em = fmaxf(em, el[j]);
        }
        float e1 = -INFINITY, e2v = -INFINITY; int i1 = 0, i2 = 0;
        #pragma unroll
        for (int j = 0; j < EPG; ++j) {
            float v = el[j];
            if (v > e1)       { e2v = e1; i2 = i1; e1 = v; i1 = j; }
            else if (v > e2v) { e2v = v; i2 = j; }
        }
        float ep[EPG]; float es = 0.f;
        #pragma unroll
        for (int j = 0; j < EPG; ++j) { ep[j] = expf(el[j] - em); es += ep[j]; }
        float inv = 1.f / es;
        #pragma unroll
        for (int j = 0; j < EPG; ++j) ep[j] *= inv;
        float u2 = (float)u2i;
        float v1 = ep[i1], v2 = ep[i2];
        float denom = v1 + v2 * u2;
        float n1 = v1 / denom, n2 = v2 * u2 / denom;
        int e1i = gi * EPG + i1, e2i = gi * EPG + i2;

        float newD = (lane == e1i ? 1.f : 0.f) + (lane == e2i ? u2 : 0.f);
        float newC = (lane == e1i ? n1 : 0.f) + (lane == e2i ? n2 : 0.f);
        float newR = ((lane >> 4) == gi) ? gp * ep[lane & 15] : 0.f;

        size_t ob = (size_t)tok * NE + lane;
        float oldD = out[ob];
        float oldR = out[(size_t)2 * T_TOKENS * NE + ob];
        out[ob] = newD;
        out[(size_t)T_TOKENS * NE + ob] = newC;
        out[(size_t)2 * T_TOKENS * NE + ob] = newR;
        float dD = newD - oldD, dR = newR - oldR;
        if (dD != 0.f) atomicAdd(&sums[lane], dD);
        if (dR != 0.f) atomicAdd(&sums[NE + lane], dR);
    }
}

__global__ void moe_finalize(const float* __restrict__ sums, float* __restrict__ out) {
    int l = threadIdx.x;
    float v = sums[l] * sums[NE + l];
    #pragma unroll
    for (int off = 32; off; off >>= 1) v += __shfl_down(v, off, 64);
    if (l == 0) {
        float N = (float)T_TOKENS;
        out[(size_t)3 * T_TOKENS * NE] = v * (float)NE / (N * N);
    }
}

extern "C" void kernel_launch(void* const* d_in, const int* in_sizes, int n_in,
                              void* d_out, int out_size, void* d_ws, size_t ws_size,
                              hipStream_t stream) {
    const float* x  = (const float*)d_in[0];
    const float* Wg = (const float*)d_in[1];
    const float* We = (const float*)d_in[2];
    const float* W1 = (const float*)d_in[3];
    const float* b1 = (const float*)d_in[4];
    const float* W2 = (const float*)d_in[5];
    const float* b2 = (const float*)d_in[6];
    const int* minE = (const int*)d_in[7];
    const int* maxE = (const int*)d_in[8];
    float* out = (float*)d_out;
    float* ws  = (float*)d_ws;

    float* wfrag = ws;
    float* part  = ws + P_OFF;
    float* sums  = ws + SUM_OFF;
    int*   cnt   = (int*)(ws + CNT_OFF);
    int4*  list  = (int4*)(ws + LIST_OFF);

    moe_zero<<<1, 256, 0, stream>>>(sums, cnt);
    moe_prep<<<64 * NT, 64, 0, stream>>>(Wg, We, W1, wfrag);
    moe_gemm<<<256 * KS, 256, 0, stream>>>(x, wfrag, part);
    moe_epi<<<T_TOKENS / 32, 256, 0, stream>>>(part, b1, W2, b2, minE, maxE,
                                               out, sums, cnt, list);
    moe_fix<<<1024, 64, 0, stream>>>(x, Wg, We, W1, b1, W2, b2, minE, maxE,
                                     out, sums, cnt, list);
    moe_finalize<<<1, 64, 0, stream>>>(sums, out);
}

// Round 4
// 149.476 us; speedup vs baseline: 6.0631x; 1.7627x over previous
//
#include <hip/hip_runtime.h>
#include <cmath>

#define T_TOKENS 16384
#define DIM 2048
#define HH 64
#define NG 4
#define EPG 16
#define NE 64
#define NJ 132
#define NJP 144          // padded to 9 n-tiles
#define NT 9
#define KS 4
#define KCHUNK (DIM / KS)        // 512
#define KSTEPS (KCHUNK / 32)     // 16
#define TAU 0.02f
#define KEPS 5e-3f

typedef __attribute__((ext_vector_type(8))) short bf16x8;
typedef __attribute__((ext_vector_type(4))) float f32x4;

// ws float-offsets
#define WF_FLOATS (64 * NT * 64 * 4)                 // 147456 (fragment-linear bf16 weights, all 64 ksteps)
#define P_OFF WF_FLOATS
#define P_FLOATS ((size_t)KS * T_TOKENS * NJP)       // 9.44M floats
#define SUM_OFF (P_OFF + P_FLOATS)                   // 128 floats: usage, rp
#define CNT_OFF (SUM_OFF + 128)
#define LIST_OFF (CNT_OFF + 4)                       // int4 entries (16B aligned)

static __device__ inline unsigned bf16rne(float x) {
    unsigned u = __float_as_uint(x);
    return (u + 0x7FFFu + ((u >> 16) & 1u)) >> 16;
}
static __device__ inline unsigned pk2trunc(float a, float b) {
    return (__float_as_uint(a) >> 16) | (__float_as_uint(b) & 0xFFFF0000u);
}
static __device__ inline bf16x8 packA(float4 a, float4 b) {
    union { unsigned u[4]; bf16x8 v; } r;
    r.u[0] = pk2trunc(a.x, a.y); r.u[1] = pk2trunc(a.z, a.w);
    r.u[2] = pk2trunc(b.x, b.y); r.u[3] = pk2trunc(b.z, b.w);
    return r.v;
}

__global__ void moe_zero(float* sums, int* cnt) {
    if (threadIdx.x < 128) sums[threadIdx.x] = 0.f;
    if (threadIdx.x == 128) *cnt = 0;
}

// Build fragment-linear bf16 weight buffer: [kstep 64][ntile 9][lane 64][16B]
__global__ void moe_prep(const float* __restrict__ Wg, const float* __restrict__ We,
                         const float* __restrict__ W1, float* __restrict__ ws) {
    int bid = blockIdx.x;                 // 576
    int kstep = bid / NT, nt = bid % NT;
    int lane = threadIdx.x;               // 64
    int row = nt * 16 + (lane & 15);
    int k0 = kstep * 32 + (lane >> 4) * 8;
    const float* src = nullptr;
    if (row < HH)            src = W1 + (size_t)row * DIM;
    else if (row < HH + NG)  src = Wg + (size_t)(row - HH) * DIM;
    else if (row < NJ)       src = We + (size_t)(row - HH - NG) * DIM;
    unsigned r0 = 0, r1 = 0, r2 = 0, r3 = 0;
    if (src) {
        r0 = bf16rne(src[k0 + 0]) | (bf16rne(src[k0 + 1]) << 16);
        r1 = bf16rne(src[k0 + 2]) | (bf16rne(src[k0 + 3]) << 16);
        r2 = bf16rne(src[k0 + 4]) | (bf16rne(src[k0 + 5]) << 16);
        r3 = bf16rne(src[k0 + 6]) | (bf16rne(src[k0 + 7]) << 16);
    }
    ((uint4*)ws)[(size_t)(kstep * NT + nt) * 64 + lane] = make_uint4(r0, r1, r2, r3);
}

__global__ __launch_bounds__(256, 4) void moe_gemm(
    const float* __restrict__ x, const float* __restrict__ wfrag,
    float* __restrict__ part) {
    const int bid = blockIdx.x;
    const int ks = bid >> 8;             // grid = 256*KS
    const int mb = bid & 255;
    const int tid = threadIdx.x;
    const int lane = tid & 63, wave = tid >> 6;
    const int l15 = lane & 15, lq = lane >> 4;
    const int tokA = mb * 64 + wave * 16 + l15;
    const float4* xp = (const float4*)(x + (size_t)tokA * DIM + ks * KCHUNK + lq * 8);
    const bf16x8* wf = (const bf16x8*)wfrag + (size_t)(ks * KSTEPS) * NT * 64 + lane;

    f32x4 acc[NT];
    #pragma unroll
    for (int n = 0; n < NT; ++n) acc[n] = (f32x4){0.f, 0.f, 0.f, 0.f};

    float4 aA0 = xp[0], aA1 = xp[1];
    bf16x8 bA[NT], bB[NT];
    #pragma unroll
    for (int n = 0; n < NT; ++n) bA[n] = wf[n * 64];
    float4 aB0, aB1;

    #pragma unroll 2
    for (int t = 0; t < KSTEPS; t += 2) {
        const int t1 = (t + 1 < KSTEPS) ? t + 1 : t;
        aB0 = xp[t1 * 8]; aB1 = xp[t1 * 8 + 1];
        #pragma unroll
        for (int n = 0; n < NT; ++n) bB[n] = wf[(t1 * NT + n) * 64];
        bf16x8 af = packA(aA0, aA1);
        #pragma unroll
        for (int n = 0; n < NT; ++n)
            acc[n] = __builtin_amdgcn_mfma_f32_16x16x32_bf16(af, bA[n], acc[n], 0, 0, 0);

        const int t2 = (t + 2 < KSTEPS) ? t + 2 : t;
        aA0 = xp[t2 * 8]; aA1 = xp[t2 * 8 + 1];
        #pragma unroll
        for (int n = 0; n < NT; ++n) bA[n] = wf[(t2 * NT + n) * 64];
        af = packA(aB0, aB1);
        #pragma unroll
        for (int n = 0; n < NT; ++n)
            acc[n] = __builtin_amdgcn_mfma_f32_16x16x32_bf16(af, bB[n], acc[n], 0, 0, 0);
    }

    // C/D: col = lane&15 (n), row = (lane>>4)*4 + r (token)
    float* po = part + (size_t)ks * T_TOKENS * NJP
              + (size_t)(mb * 64 + wave * 16 + lq * 4) * NJP + l15;
    #pragma unroll
    for (int n = 0; n < NT; ++n)
        #pragma unroll
        for (int r = 0; r < 4; ++r)
            po[(size_t)r * NJP + n * 16] = acc[n][r];
}

// epilogue: 256 blocks x 64 tokens
__global__ __launch_bounds__(256, 2) void moe_epi(
    const float* __restrict__ part,
    const float* __restrict__ b1, const float* __restrict__ W2,
    const float* __restrict__ b2, const int* __restrict__ minE,
    const int* __restrict__ maxE, float* __restrict__ out,
    float* __restrict__ sums, int* __restrict__ cnt, int4* __restrict__ list) {
    __shared__ float ot[64 * 133];
    __shared__ float rp_s[64 * 17];
    __shared__ float sc_n1[64], sc_n2[64], sc_u2[64];
    __shared__ int   sc_e1[64], sc_e2[64], sc_g[64];
    __shared__ float s_usage[NE], s_rp[NE];
    const int tid = threadIdx.x;
    const int T0 = blockIdx.x * 64;
    if (tid < NE) { s_usage[tid] = 0.f; s_rp[tid] = 0.f; }

    for (int idx = tid; idx < 64 * NJ; idx += 256) {
        int t = idx / NJ, j = idx % NJ;
        float v = part[(size_t)(T0 + t) * NJP + j];
        #pragma unroll
        for (int p = 1; p < KS; ++p)
            v += part[(size_t)p * T_TOKENS * NJP + (size_t)(T0 + t) * NJP + j];
        ot[t * 133 + j] = v;
    }
    __syncthreads();

    if (tid < 64) {
        const int t = tid, tok = T0 + t;
        const float* o = &ot[t * 133];

        float z = b2[0];
        #pragma unroll 8
        for (int i = 0; i < HH; ++i) {
            float h = o[i] + b1[i];
            z = fmaf(W2[i], h > 0.f ? h : 0.f, z);
        }
        float c = 1.f / (1.f + expf(-z));
        int mx = maxE[0], mn = minE[0];
        float y = c * (float)mx;
        int k = (int)y; k = k < mn ? mn : (k > mx ? mx : k);
        int kl = (int)(y - KEPS); kl = kl < mn ? mn : (kl > mx ? mx : kl);
        int kh = (int)(y + KEPS); kh = kh < mn ? mn : (kh > mx ? mx : kh);
        bool flagK = (kl != kh);
        float u2 = (k >= 2) ? 1.f : 0.f;

        float gl[NG]; float gm = -INFINITY; int gi = 0;
        #pragma unroll
        for (int g = 0; g < NG; ++g) {
            gl[g] = o[HH + g];
            if (gl[g] > gm) { gm = gl[g]; gi = g; }
        }
        float g2 = -INFINITY;
        #pragma unroll
        for (int g = 0; g < NG; ++g) if (g != gi && gl[g] > g2) g2 = gl[g];
        bool flagG = (gm - g2) < TAU;
        float gsum = 0.f;
        #pragma unroll
        for (int g = 0; g < NG; ++g) gsum += expf(gl[g] - gm);
        float gp = 1.f / gsum;

        float el[EPG];
        #pragma unroll
        for (int j = 0; j < EPG; ++j) el[j] = o[HH + NG + gi * EPG + j];
        float e1 = -INFINITY, e2v = -INFINITY, e3v = -INFINITY; int i1 = 0, i2 = 0;
        #pragma unroll
        for (int j = 0; j < EPG; ++j) {
            float v = el[j];
            if (v > e1)       { e3v = e2v; e2v = e1; i2 = i1; e1 = v; i1 = j; }
            else if (v > e2v) { e3v = e2v; e2v = v; i2 = j; }
            else if (v > e3v) { e3v = v; }
        }
        bool flagE = ((e1 - e2v) < TAU) || (u2 > 0.f && (e2v - e3v) < TAU);

        float ep[EPG]; float es = 0.f;
        #pragma unroll
        for (int j = 0; j < EPG; ++j) { ep[j] = expf(el[j] - e1); es += ep[j]; }
        float inv = 1.f / es;
        #pragma unroll
        for (int j = 0; j < EPG; ++j) ep[j] *= inv;
        float v1 = ep[i1], v2 = ep[i2];
        float denom = v1 + v2 * u2;
        sc_n1[t] = v1 / denom; sc_n2[t] = v2 * u2 / denom; sc_u2[t] = u2;
        sc_e1[t] = gi * EPG + i1; sc_e2[t] = gi * EPG + i2; sc_g[t] = gi;
        #pragma unroll
        for (int j = 0; j < EPG; ++j) rp_s[t * 17 + j] = gp * ep[j];

        if (flagK || flagG || flagE) {
            int p = atomicAdd(cnt, 1);
            int fl = (flagG ? 1 : 0) | (flagE ? 2 : 0) | (flagK ? 4 : 0);
            list[p] = make_int4(tok, fl, (int)u2, 0);
        }
    }
    __syncthreads();

    float* outD = out;
    float* outC = out + (size_t)T_TOKENS * NE;
    float* outR = out + (size_t)2 * T_TOKENS * NE;
    for (int idx = tid; idx < 64 * NE; idx += 256) {
        int t = idx >> 6, e = idx & 63;
        int e1i = sc_e1[t], e2i = sc_e2[t];
        float disp = (e == e1i ? 1.f : 0.f) + (e == e2i ? sc_u2[t] : 0.f);
        float comb = (e == e1i ? sc_n1[t] : 0.f) + (e == e2i ? sc_n2[t] : 0.f);
        float rpv  = ((e >> 4) == sc_g[t]) ? rp_s[t * 17 + (e & 15)] : 0.f;
        size_t ob = (size_t)(T0 + t) * NE + e;
        outD[ob] = disp; outC[ob] = comb; outR[ob] = rpv;
        atomicAdd(&s_usage[e], disp);
        atomicAdd(&s_rp[e], rpv);
    }
    __syncthreads();
    if (tid < NE) {
        atomicAdd(&sums[tid], s_usage[tid]);
        atomicAdd(&sums[NE + tid], s_rp[tid]);
    }
}

// parallel fixup: one block (4 waves) per flagged token
__global__ __launch_bounds__(256, 4) void moe_fix(
    const float* __restrict__ x, const float* __restrict__ Wg,
    const float* __restrict__ We, const float* __restrict__ W1,
    const float* __restrict__ b1, const float* __restrict__ W2,
    const float* __restrict__ b2, const int* __restrict__ minE,
    const int* __restrict__ maxE, float* __restrict__ out,
    float* __restrict__ sums, const int* __restrict__ cnt,
    const int4* __restrict__ list) {
    __shared__ float gl_s[NG];
    __shared__ float h_s[HH];
    __shared__ float el_s[EPG];
    __shared__ float rp_row[EPG];
    __shared__ int   s_gi;
    __shared__ float s_u2, s_gp;
    __shared__ int   s_e1, s_e2;
    __shared__ float s_n1, s_n2;

    const int tid = threadIdx.x;
    const int wave = tid >> 6, lane = tid & 63;
    const int n = *cnt;

    for (int i = blockIdx.x; i < n; i += gridDim.x) {
        const int4 ent = list[i];
        const int tok = ent.x, fl = ent.y;
        const float u2_in = (float)ent.z;

        const float* xrow = x + (size_t)tok * DIM;
        float xr[32];
        #pragma unroll
        for (int m = 0; m < 32; ++m) xr[m] = xrow[lane + m * 64];

        auto dotf = [&](const float* w) -> float {
            float s = 0.f;
            #pragma unroll
            for (int m = 0; m < 32; ++m) s = fmaf(xr[m], w[lane + m * 64], s);
            #pragma unroll
            for (int off = 32; off; off >>= 1) s += __shfl_xor(s, off, 64);
            return s;
        };

        // phase 1: exact group logits (1 dot per wave) + exact h if k uncertain
        {
            float g = dotf(Wg + (size_t)wave * DIM);
            if (lane == 0) gl_s[wave] = g;
        }
        if (fl & 4) {
            for (int j = wave; j < HH; j += 4) {
                float hv = dotf(W1 + (size_t)j * DIM);
                if (lane == 0) h_s[j] = hv;
            }
        }
        __syncthreads();

        if (tid == 0) {
            float gm = -INFINITY; int gi = 0;
            #pragma unroll
            for (int g = 0; g < NG; ++g)
                if (gl_s[g] > gm) { gm = gl_s[g]; gi = g; }
            float gsum = 0.f;
            #pragma unroll
            for (int g = 0; g < NG; ++g) gsum += expf(gl_s[g] - gm);
            s_gp = 1.f / gsum;
            s_gi = gi;
            float u2 = u2_in;
            if (fl & 4) {
                float z = b2[0];
                for (int j = 0; j < HH; ++j) {
                    float h = h_s[j] + b1[j];
                    z = fmaf(W2[j], h > 0.f ? h : 0.f, z);
                }
                float c = 1.f / (1.f + expf(-z));
                int mx = maxE[0], mn = minE[0];
                int k = (int)(c * (float)mx);
                k = k < mn ? mn : (k > mx ? mx : k);
                u2 = (k >= 2) ? 1.f : 0.f;
            }
            s_u2 = u2;
        }
        __syncthreads();

        // phase 2: exact expert logits for exact group (4 dots per wave)
        const int gi = s_gi;
        for (int j = wave; j < EPG; j += 4) {
            float e = dotf(We + (size_t)(gi * EPG + j) * DIM);
            if (lane == 0) el_s[j] = e;
        }
        __syncthreads();

        if (tid == 0) {
            float e1 = -INFINITY, e2v = -INFINITY; int i1 = 0, i2 = 0;
            #pragma unroll
            for (int j = 0; j < EPG; ++j) {
                float v = el_s[j];
                if (v > e1)       { e2v = e1; i2 = i1; e1 = v; i1 = j; }
                else if (v > e2v) { e2v = v; i2 = j; }
            }
            float es = 0.f;
            #pragma unroll
            for (int j = 0; j < EPG; ++j) {
                float e = expf(el_s[j] - e1);
                rp_row[j] = e;   // unnormalized for now
                es += e;
            }
            float inv = 1.f / es;
            float gp = s_gp;
            #pragma unroll
            for (int j = 0; j < EPG; ++j) rp_row[j] *= inv * gp;
            float v1 = expf(el_s[i1] - e1) * inv;   // = max prob
            float v2 = expf(el_s[i2] - e1) * inv;
            float u2 = s_u2;
            float denom = v1 + v2 * u2;
            s_n1 = v1 / denom; s_n2 = v2 * u2 / denom;
            s_e1 = gi * EPG + i1; s_e2 = gi * EPG + i2;
        }
        __syncthreads();

        if (tid < NE) {
            const int e = tid;
            float u2 = s_u2;
            float newD = (e == s_e1 ? 1.f : 0.f) + (e == s_e2 ? u2 : 0.f);
            float newC = (e == s_e1 ? s_n1 : 0.f) + (e == s_e2 ? s_n2 : 0.f);
            float newR = ((e >> 4) == gi) ? rp_row[e & 15] : 0.f;
            size_t ob = (size_t)tok * NE + e;
            float oldD = out[ob];
            float oldR = out[(size_t)2 * T_TOKENS * NE + ob];
            out[ob] = newD;
            out[(size_t)T_TOKENS * NE + ob] = newC;
            out[(size_t)2 * T_TOKENS * NE + ob] = newR;
            float dD = newD - oldD, dR = newR - oldR;
            if (dD != 0.f) atomicAdd(&sums[e], dD);
            if (dR != 0.f) atomicAdd(&sums[NE + e], dR);
        }
        __syncthreads();
    }
}

__global__ void moe_finalize(const float* __restrict__ sums, float* __restrict__ out) {
    int l = threadIdx.x;
    float v = sums[l] * sums[NE + l];
    #pragma unroll
    for (int off = 32; off; off >>= 1) v += __shfl_down(v, off, 64);
    if (l == 0) {
        float N = (float)T_TOKENS;
        out[(size_t)3 * T_TOKENS * NE] = v * (float)NE / (N * N);
    }
}

extern "C" void kernel_launch(void* const* d_in, const int* in_sizes, int n_in,
                              void* d_out, int out_size, void* d_ws, size_t ws_size,
                              hipStream_t stream) {
    const float* x  = (const float*)d_in[0];
    const float* Wg = (const float*)d_in[1];
    const float* We = (const float*)d_in[2];
    const float* W1 = (const float*)d_in[3];
    const float* b1 = (const float*)d_in[4];
    const float* W2 = (const float*)d_in[5];
    const float* b2 = (const float*)d_in[6];
    const int* minE = (const int*)d_in[7];
    const int* maxE = (const int*)d_in[8];
    float* out = (float*)d_out;
    float* ws  = (float*)d_ws;

    float* wfrag = ws;
    float* part  = ws + P_OFF;
    float* sums  = ws + SUM_OFF;
    int*   cnt   = (int*)(ws + CNT_OFF);
    int4*  list  = (int4*)(ws + LIST_OFF);

    moe_zero<<<1, 256, 0, stream>>>(sums, cnt);
    moe_prep<<<64 * NT, 64, 0, stream>>>(Wg, We, W1, wfrag);
    moe_gemm<<<256 * KS, 256, 0, stream>>>(x, wfrag, part);
    moe_epi<<<T_TOKENS / 64, 256, 0, stream>>>(part, b1, W2, b2, minE, maxE,
                                               out, sums, cnt, list);
    moe_fix<<<2048, 256, 0, stream>>>(x, Wg, We, W1, b1, W2, b2, minE, maxE,
                                      out, sums, cnt, list);
    moe_finalize<<<1, 64, 0, stream>>>(sums, out);
}